// Round 12
// baseline (91.994 us; speedup 1.0000x reference)
//
#include <hip/hip_runtime.h>

#define Hc     512
#define Wc     512
#define OH     506
#define OW     506
#define NPIX   (Hc * Wc)
#define BATCH  64
#define CHUNKS 16

#define BH     8                           // output rows per band
#define NBAND  64                          // 63*8=504, band 63 covers 504-505
#define WPB    4                           // waves (bands) per block
#define BLK_PER_IMG (NBAND / WPB)          // 16
#define NBLK   (BATCH * BLK_PER_IMG)       // 1024 (%8==0 -> bijective swizzle)
#define IMGS_PER_XCD (BATCH / 8)           // 8
#define NPART  NBLK

typedef float f32x2 __attribute__((ext_vector_type(2)));
typedef float f32x4 __attribute__((ext_vector_type(4)));

// ---------------- Kernel 1: per-(sample,chunk) min/max partials -------------
__global__ __launch_bounds__(256) void mm_part_kernel(
    const float* __restrict__ X, const float* __restrict__ Y,
    float* __restrict__ part)
{
    int blk = blockIdx.x;            // 0 .. BATCH*CHUNKS-1
    int b   = blk >> 4;
    int ch  = blk & 15;
    size_t base = (size_t)b * NPIX + (size_t)ch * (NPIX / CHUNKS);
    const float4* x4 = (const float4*)(X + base);
    const float4* y4 = (const float4*)(Y + base);
    const int n4 = (NPIX / CHUNKS) / 4;   // 4096

    float mn = 1e38f, mx = -1e38f;
    for (int i = threadIdx.x; i < n4; i += 256) {
        float4 a = x4[i];
        float4 c = y4[i];
        mn = fminf(mn, fminf(fminf(a.x, a.y), fminf(a.z, a.w)));
        mx = fmaxf(mx, fmaxf(fmaxf(a.x, a.y), fmaxf(a.z, a.w)));
        mn = fminf(mn, fminf(fminf(c.x, c.y), fminf(c.z, c.w)));
        mx = fmaxf(mx, fmaxf(fmaxf(c.x, c.y), fmaxf(c.z, c.w)));
    }
    #pragma unroll
    for (int off = 1; off < 64; off <<= 1) {
        mn = fminf(mn, __shfl_xor(mn, off, 64));
        mx = fmaxf(mx, __shfl_xor(mx, off, 64));
    }
    __shared__ float smn[4], smx[4];
    int lane = threadIdx.x & 63, wid = threadIdx.x >> 6;
    if (lane == 0) { smn[wid] = mn; smx[wid] = mx; }
    __syncthreads();
    if (threadIdx.x == 0) {
        mn = fminf(fminf(smn[0], smn[1]), fminf(smn[2], smn[3]));
        mx = fmaxf(fmaxf(smx[0], smx[1]), fmaxf(smx[2], smx[3]));
        part[2 * blk]     = mn;
        part[2 * blk + 1] = mx;
    }
}

// ---------------- Kernel 2: 8-col/lane full-row streaming SSIM --------------
// One wave spans all 512 cols (8 cols/lane, 2x dwordx4 per image per row).
// Horizontal 7-window: in-lane prefix sums + 6 shuffles/stat from lane+1.
// Vertical 7-window: running sums + re-load of outgoing row (L1/L2-hot).
// No LDS staging, no barriers, no clamps. XCD-affine band-block mapping.
__global__ __launch_bounds__(256, 4) void ssim_stream_kernel(
    const float* __restrict__ X, const float* __restrict__ Y,
    const float* __restrict__ mmpart, float* __restrict__ part)
{
    const int lane = threadIdx.x & 63;
    const int wid  = threadIdx.x >> 6;

    // XCD-affine swizzle (bijective: NBLK % 8 == 0)
    const int lin  = blockIdx.x;             // 0..1023
    const int xcd  = lin & 7;
    const int slot = lin >> 3;               // 0..127
    const int img  = xcd * IMGS_PER_XCD + (slot >> 4);   // 0..63
    const int blk  = slot & 15;              // band-block within image
    const int band = blk * WPB + wid;        // 0..63

    // fold chunk min/max -> C1, C2 (uniform; L2-hot, hidden under prologue)
    float mn = 1e38f, mx = -1e38f;
    #pragma unroll
    for (int ch = 0; ch < CHUNKS; ++ch) {
        mn = fminf(mn, mmpart[2 * (img * CHUNKS + ch)]);
        mx = fmaxf(mx, mmpart[2 * (img * CHUNKS + ch) + 1]);
    }
    const float dr = mx - mn;
    const float C1 = (0.01f * dr) * (0.01f * dr);
    const float C2 = (0.03f * dr) * (0.03f * dr);
    const f32x2 C1v = {C1, C1};
    const f32x2 C2v = {C2, C2};
    const f32x2 inv2  = {1.0f / 49.0f, 1.0f / 49.0f};
    const f32x2 covn2 = {49.0f / 48.0f, 49.0f / 48.0f};

    // output-validity masks: lane owns cols 8*lane .. 8*lane+7
    f32x2 vm01 = {1.f, 1.f}, vm23 = {1.f, 1.f};
    f32x2 vm45 = {1.f, 1.f}, vm67 = {1.f, 1.f};
    if (lane == 63) {                         // cols 504..511: only 504,505 valid
        vm23 = (f32x2){0.f, 0.f};
        vm45 = (f32x2){0.f, 0.f};
        vm67 = (f32x2){0.f, 0.f};
    }

    const int oy0 = band * BH;
    const int nvalid = (OH - oy0) < BH ? (OH - oy0) : BH;   // 8, or 2 (band 63)

    const float* px = X + (size_t)img * NPIX + 8 * lane;
    const float* py = Y + (size_t)img * NPIX + 8 * lane;

    // packed running vertical sums: V*[i] = cols {2i, 2i+1}
    f32x2 Vx[4]  = {{0,0},{0,0},{0,0},{0,0}};
    f32x2 Vy[4]  = {{0,0},{0,0},{0,0},{0,0}};
    f32x2 Vxy[4] = {{0,0},{0,0},{0,0},{0,0}};
    f32x2 Vss[4] = {{0,0},{0,0},{0,0},{0,0}};

    #define VADD8(xa0, xa1, ya0, ya1)                                        \
    {                                                                        \
        f32x2 x0 = (xa0).lo, x1 = (xa0).hi, x2 = (xa1).lo, x3 = (xa1).hi;    \
        f32x2 y0 = (ya0).lo, y1 = (ya0).hi, y2 = (ya1).lo, y3 = (ya1).hi;    \
        Vx[0] += x0; Vx[1] += x1; Vx[2] += x2; Vx[3] += x3;                  \
        Vy[0] += y0; Vy[1] += y1; Vy[2] += y2; Vy[3] += y3;                  \
        Vxy[0] += x0 * y0; Vxy[1] += x1 * y1;                                \
        Vxy[2] += x2 * y2; Vxy[3] += x3 * y3;                                \
        Vss[0] += x0 * x0 + y0 * y0; Vss[1] += x1 * x1 + y1 * y1;            \
        Vss[2] += x2 * x2 + y2 * y2; Vss[3] += x3 * x3 + y3 * y3;            \
    }
    #define VSUB8(xa0, xa1, ya0, ya1)                                        \
    {                                                                        \
        f32x2 x0 = (xa0).lo, x1 = (xa0).hi, x2 = (xa1).lo, x3 = (xa1).hi;    \
        f32x2 y0 = (ya0).lo, y1 = (ya0).hi, y2 = (ya1).lo, y3 = (ya1).hi;    \
        Vx[0] -= x0; Vx[1] -= x1; Vx[2] -= x2; Vx[3] -= x3;                  \
        Vy[0] -= y0; Vy[1] -= y1; Vy[2] -= y2; Vy[3] -= y3;                  \
        Vxy[0] -= x0 * y0; Vxy[1] -= x1 * y1;                                \
        Vxy[2] -= x2 * y2; Vxy[3] -= x3 * y3;                                \
        Vss[0] -= x0 * x0 + y0 * y0; Vss[1] -= x1 * x1 + y1 * y1;            \
        Vss[2] -= x2 * x2 + y2 * y2; Vss[3] -= x3 * x3 + y3 * y3;            \
    }

    // prologue: accumulate rows oy0..oy0+5 (max row 509, no clamp)
    #pragma unroll
    for (int k = 0; k < 6; ++k) {
        const float* rx = px + (size_t)(oy0 + k) * Wc;
        const float* ry = py + (size_t)(oy0 + k) * Wc;
        f32x4 xa0 = *(const f32x4*)rx;
        f32x4 xa1 = *(const f32x4*)(rx + 4);
        f32x4 ya0 = *(const f32x4*)ry;
        f32x4 ya1 = *(const f32x4*)(ry + 4);
        VADD8(xa0, xa1, ya0, ya1)
    }

    f32x2 acc2 = {0.f, 0.f};

    // horizontal 7-window via in-lane prefix sums + 6 neighbor shuffles
    // W_j = P_{j+7} - P_j  (P0 = 0, P_{8+m} = P8 + neighbor.P_m)
    #define H7_8(V, Wa, Wb, Wc_, Wd)                                         \
    {                                                                        \
        float c0 = V[0].x, c1 = V[0].y, c2 = V[1].x, c3 = V[1].y;            \
        float c4 = V[2].x, c5 = V[2].y, c6 = V[3].x, c7 = V[3].y;            \
        float P1 = c0,      P2 = P1 + c1, P3 = P2 + c2, P4 = P3 + c3;        \
        float P5 = P4 + c4, P6 = P5 + c5, P7 = P6 + c6, P8 = P7 + c7;        \
        float N1 = __shfl_down(P1, 1, 64);                                   \
        float N2 = __shfl_down(P2, 1, 64);                                   \
        float N3 = __shfl_down(P3, 1, 64);                                   \
        float N4 = __shfl_down(P4, 1, 64);                                   \
        float N5 = __shfl_down(P5, 1, 64);                                   \
        float N6 = __shfl_down(P6, 1, 64);                                   \
        Wa = (f32x2){P7,             P8 - P1};                               \
        Wb = (f32x2){(P8 + N1) - P2, (P8 + N2) - P3};                        \
        Wc_ = (f32x2){(P8 + N3) - P4, (P8 + N4) - P5};                       \
        Wd = (f32x2){(P8 + N5) - P6, (P8 + N6) - P7};                        \
    }

    #define SSIM2(wx, wy, wp, ws, vmv)                                       \
    {                                                                        \
        f32x2 ux   = wx * inv2;                                              \
        f32x2 uy   = wy * inv2;                                              \
        f32x2 uxuy = ux * uy;                                                \
        f32x2 u2   = ux * ux + uy * uy;                                      \
        f32x2 vxy  = (wp * inv2 - uxuy) * covn2;                             \
        f32x2 vss  = (ws * inv2 - u2) * covn2;                               \
        f32x2 A1   = uxuy + uxuy + C1v;                                      \
        f32x2 A2   = vxy + vxy + C2v;                                        \
        f32x2 B1   = u2 + C1v;                                               \
        f32x2 B2   = vss + C2v;                                              \
        f32x2 den  = B1 * B2;                                                \
        f32x2 num  = A1 * A2;                                                \
        f32x2 rv   = {__builtin_amdgcn_rcpf(den.x),                          \
                      __builtin_amdgcn_rcpf(den.y)};                         \
        acc2 += num * rv * vmv;                                              \
    }

    // running row pointers
    const float* pxi = px + (size_t)(oy0 + 6) * Wc;
    const float* pyi = py + (size_t)(oy0 + 6) * Wc;
    const float* pxo = px + (size_t)oy0 * Wc;
    const float* pyo = py + (size_t)oy0 * Wc;

    #pragma unroll 2
    for (int tt = 0; tt < nvalid; ++tt) {
        f32x4 xi0 = *(const f32x4*)pxi;
        f32x4 xi1 = *(const f32x4*)(pxi + 4); pxi += Wc;
        f32x4 yi0 = *(const f32x4*)pyi;
        f32x4 yi1 = *(const f32x4*)(pyi + 4); pyi += Wc;
        VADD8(xi0, xi1, yi0, yi1)

        f32x2 Wx01, Wx23, Wx45, Wx67;  H7_8(Vx,  Wx01, Wx23, Wx45, Wx67)
        f32x2 Wy01, Wy23, Wy45, Wy67;  H7_8(Vy,  Wy01, Wy23, Wy45, Wy67)
        f32x2 Wp01, Wp23, Wp45, Wp67;  H7_8(Vxy, Wp01, Wp23, Wp45, Wp67)
        f32x2 Ws01, Ws23, Ws45, Ws67;  H7_8(Vss, Ws01, Ws23, Ws45, Ws67)

        SSIM2(Wx01, Wy01, Wp01, Ws01, vm01)
        SSIM2(Wx23, Wy23, Wp23, Ws23, vm23)
        SSIM2(Wx45, Wy45, Wp45, Ws45, vm45)
        SSIM2(Wx67, Wy67, Wp67, Ws67, vm67)

        f32x4 xo0 = *(const f32x4*)pxo;
        f32x4 xo1 = *(const f32x4*)(pxo + 4); pxo += Wc;
        f32x4 yo0 = *(const f32x4*)pyo;
        f32x4 yo1 = *(const f32x4*)(pyo + 4); pyo += Wc;
        VSUB8(xo0, xo1, yo0, yo1)
    }

    #undef SSIM2
    #undef H7_8
    #undef VADD8
    #undef VSUB8

    float acc = acc2.x + acc2.y;
    // deterministic wave reduce + cross-wave LDS fold (one partial per block)
    #pragma unroll
    for (int off = 1; off < 64; off <<= 1)
        acc += __shfl_xor(acc, off, 64);
    __shared__ float sacc[4];
    if (lane == 0) sacc[wid] = acc;
    __syncthreads();
    if (threadIdx.x == 0)
        part[lin] = (sacc[0] + sacc[1]) + (sacc[2] + sacc[3]);
}

// ---------------- Kernel 3: final deterministic f64 reduction ---------------
__global__ __launch_bounds__(1024) void final_reduce_kernel(
    const float* __restrict__ part, float* __restrict__ out)
{
    __shared__ double sd[1024];
    double s = 0.0;
    for (int i = threadIdx.x; i < NPART; i += 1024)
        s += (double)part[i];
    sd[threadIdx.x] = s;
    __syncthreads();
    for (int off = 512; off > 0; off >>= 1) {
        if (threadIdx.x < off) sd[threadIdx.x] += sd[threadIdx.x + off];
        __syncthreads();
    }
    if (threadIdx.x == 0)
        out[0] = (float)(sd[0] / ((double)BATCH * OH * OW));
}

extern "C" void kernel_launch(void* const* d_in, const int* in_sizes, int n_in,
                              void* d_out, int out_size, void* d_ws, size_t ws_size,
                              hipStream_t stream) {
    const float* X = (const float*)d_in[0];
    const float* Y = (const float*)d_in[1];
    float* out = (float*)d_out;
    float* ws  = (float*)d_ws;

    float* mmpart = ws;                   // 2 * BATCH * CHUNKS = 2048 floats
    float* part   = ws + 2048;            // NPART = 1024 floats

    mm_part_kernel<<<BATCH * CHUNKS, 256, 0, stream>>>(X, Y, mmpart);
    ssim_stream_kernel<<<NBLK, 64 * WPB, 0, stream>>>(X, Y, mmpart, part);
    final_reduce_kernel<<<1, 1024, 0, stream>>>(part, out);
}

// Round 13
// 75.785 us; speedup vs baseline: 1.2139x; 1.2139x over previous
//
#include <hip/hip_runtime.h>

#define Hc     512
#define Wc     512
#define OH     506
#define OW     506
#define NPIX   (Hc * Wc)
#define BATCH  64
#define CHUNKS 32

#define BH     16                          // output rows per band
#define NBAND  32                          // 31*16=496, band 31 covers 496-505
#define NW     3                           // col-chunks (strips) per image row
#define WPB    4                           // waves (bands) per block
#define BLK_PER_STRIP (NBAND / WPB)        // 8
#define NSTRIP (BATCH * NW)                // 192
#define NBLK   (NSTRIP * BLK_PER_STRIP)    // 1536  (%8==0 -> bijective swizzle)
#define STRIPS_PER_XCD (NSTRIP / 8)        // 24
#define NPART  NBLK                        // one partial per block

typedef float f32x2 __attribute__((ext_vector_type(2)));
typedef float f32x4 __attribute__((ext_vector_type(4)));

// ---------------- Kernel 1: per-(sample,chunk) min/max partials -------------
__global__ __launch_bounds__(256) void mm_part_kernel(
    const float* __restrict__ X, const float* __restrict__ Y,
    float* __restrict__ part)
{
    int blk = blockIdx.x;            // 0 .. BATCH*CHUNKS-1
    int b   = blk >> 5;
    int ch  = blk & 31;
    size_t base = (size_t)b * NPIX + (size_t)ch * (NPIX / CHUNKS);
    const float4* x4 = (const float4*)(X + base);
    const float4* y4 = (const float4*)(Y + base);
    const int n4 = (NPIX / CHUNKS) / 4;   // 2048

    float mn = 1e38f, mx = -1e38f;
    for (int i = threadIdx.x; i < n4; i += 256) {
        float4 a = x4[i];
        float4 c = y4[i];
        mn = fminf(mn, fminf(fminf(a.x, a.y), fminf(a.z, a.w)));
        mx = fmaxf(mx, fmaxf(fmaxf(a.x, a.y), fmaxf(a.z, a.w)));
        mn = fminf(mn, fminf(fminf(c.x, c.y), fminf(c.z, c.w)));
        mx = fmaxf(mx, fmaxf(fmaxf(c.x, c.y), fmaxf(c.z, c.w)));
    }
    #pragma unroll
    for (int off = 1; off < 64; off <<= 1) {
        mn = fminf(mn, __shfl_xor(mn, off, 64));
        mx = fmaxf(mx, __shfl_xor(mx, off, 64));
    }
    __shared__ float smn[4], smx[4];
    int lane = threadIdx.x & 63, wid = threadIdx.x >> 6;
    if (lane == 0) { smn[wid] = mn; smx[wid] = mx; }
    __syncthreads();
    if (threadIdx.x == 0) {
        mn = fminf(fminf(smn[0], smn[1]), fminf(smn[2], smn[3]));
        mx = fmaxf(fmaxf(smx[0], smx[1]), fmaxf(smx[2], smx[3]));
        part[2 * blk]     = mn;
        part[2 * blk + 1] = mx;
    }
}

// ---------------- Kernel 2: streaming SSIM, XCD-affine, single-round --------
// R11 structure (verified best). SSIM uses 49^2-prescaled factors:
//   F1 = 2 Wx Wy + 2401 C1          F3 = Wx^2 + Wy^2 + 2401 C1
//   F2 = 2 covn (49 Wp - Wx Wy) + 2401 C2
//   F4 = covn (49 Ws - Wx^2 - Wy^2) + 2401 C2      S = F1 F2 / (F3 F4)
__global__ __launch_bounds__(256, 8) void ssim_stream_kernel(
    const float* __restrict__ X, const float* __restrict__ Y,
    const float* __restrict__ mmpart, float* __restrict__ part)
{
    const int lane = threadIdx.x & 63;
    const int wid  = threadIdx.x >> 6;

    // XCD-affine swizzle (bijective: NBLK % 8 == 0)
    const int lin   = blockIdx.x;            // 0..1535
    const int xcd   = lin & 7;
    const int slot  = lin >> 3;              // 0..191
    const int strip_local = slot >> 3;       // 0..23
    const int blk   = slot & 7;              // band-block within strip
    const int strip = xcd * STRIPS_PER_XCD + strip_local;   // 0..191
    const int img   = strip / NW;
    const int chunk = strip - img * NW;      // 0..2
    const int band  = blk * WPB + wid;       // 0..31

    // fold chunk min/max -> C1, C2 (uniform; L2-hot, hidden under prologue)
    float mn = 1e38f, mx = -1e38f;
    #pragma unroll
    for (int ch = 0; ch < CHUNKS; ++ch) {
        mn = fminf(mn, mmpart[2 * (img * CHUNKS + ch)]);
        mx = fmaxf(mx, mmpart[2 * (img * CHUNKS + ch) + 1]);
    }
    const float dr  = mx - mn;
    const float C1p = 2401.0f * (0.01f * dr) * (0.01f * dr);
    const float C2p = 2401.0f * (0.03f * dr) * (0.03f * dr);
    const f32x2 C1v = {C1p, C1p};
    const f32x2 C2v = {C2p, C2p};
    const f32x2 k49   = {49.0f, 49.0f};
    const f32x2 covn1 = {49.0f / 48.0f, 49.0f / 48.0f};
    const f32x2 covn2 = {2.0f * 49.0f / 48.0f, 2.0f * 49.0f / 48.0f};

    // chunk geometry
    const int cbase  = (chunk == 0) ? 0 : (chunk == 1) ? 248 : 496;
    const int out_lo = (chunk == 0) ? 0 : (chunk == 1) ? 250 : 498;
    const int out_hi = (chunk == 0) ? 249 : (chunk == 1) ? 497 : 505;

    const int col0  = cbase + 4 * lane;             // logical first col
    const int col0c = (col0 < 508) ? col0 : 508;    // clamped, 16B aligned
    f32x2 vm01, vm23;
    {
        float v[4];
        #pragma unroll
        for (int j = 0; j < 4; ++j) {
            int oc = col0 + j;
            v[j] = (oc >= out_lo && oc <= out_hi) ? 1.0f : 0.0f;
        }
        vm01 = (f32x2){v[0], v[1]};
        vm23 = (f32x2){v[2], v[3]};
    }

    const int oy0 = band * BH;
    const int nvalid = (OH - oy0) < BH ? (OH - oy0) : BH;   // 16, or 10 (band 31)

    const float* px = X + (size_t)img * NPIX + col0c;
    const float* py = Y + (size_t)img * NPIX + col0c;

    // packed running vertical sums: [0]=cols 0,1  [1]=cols 2,3
    f32x2 Vx[2]  = {{0,0},{0,0}}, Vy[2]  = {{0,0},{0,0}};
    f32x2 Vxy[2] = {{0,0},{0,0}}, Vss[2] = {{0,0},{0,0}};

    #define VADD(xa, ya)                                                     \
    {                                                                        \
        f32x2 xl = (xa).lo, xh = (xa).hi, yl = (ya).lo, yh = (ya).hi;        \
        Vx[0] += xl; Vx[1] += xh; Vy[0] += yl; Vy[1] += yh;                  \
        Vxy[0] += xl * yl; Vxy[1] += xh * yh;                                \
        Vss[0] += xl * xl + yl * yl; Vss[1] += xh * xh + yh * yh;            \
    }
    #define VSUB(xa, ya)                                                     \
    {                                                                        \
        f32x2 xl = (xa).lo, xh = (xa).hi, yl = (ya).lo, yh = (ya).hi;        \
        Vx[0] -= xl; Vx[1] -= xh; Vy[0] -= yl; Vy[1] -= yh;                  \
        Vxy[0] -= xl * yl; Vxy[1] -= xh * yh;                                \
        Vss[0] -= xl * xl + yl * yl; Vss[1] -= xh * xh + yh * yh;            \
    }

    // prologue: accumulate rows oy0..oy0+5 (max 501, no clamp)
    #pragma unroll
    for (int k = 0; k < 6; ++k) {
        f32x4 xa = *(const f32x4*)(px + (size_t)(oy0 + k) * Wc);
        f32x4 ya = *(const f32x4*)(py + (size_t)(oy0 + k) * Wc);
        VADD(xa, ya)
    }

    f32x2 acc2 = {0.f, 0.f};

    // horizontal 7-window via prefix-shuffles: 4 DS ops per stat
    #define H7(V, W0, W1, W2, W3)                                            \
    {                                                                        \
        float v0 = V[0].x, v1 = V[0].y, v2 = V[1].x, v3 = V[1].y;            \
        float t01 = v0 + v1, u23 = v2 + v3;                                  \
        float P3 = t01 + v2, P4 = t01 + u23;                                 \
        float A3 = __shfl_down(P3, 1, 64);                                   \
        float A4 = __shfl_down(P4, 1, 64);                                   \
        float B1 = __shfl_down(v0, 2, 64);                                   \
        float B2 = __shfl_down(t01, 2, 64);                                  \
        float cc = u23 + A4;                                                 \
        W0 = P4 + A3;                                                        \
        W1 = cc + v1;                                                        \
        W2 = cc + B1;                                                        \
        W3 = (v3 + A4) + B2;                                                 \
    }

    // 49^2-prescaled SSIM for a packed pair of columns
    #define SSIM2(wx, wy, wp, ws, vmv)                                       \
    {                                                                        \
        f32x2 t1  = wx * wy;                                                 \
        f32x2 sq  = wx * wx + wy * wy;                                       \
        f32x2 F1  = t1 + t1 + C1v;                                           \
        f32x2 d1  = k49 * wp - t1;                                           \
        f32x2 F2  = covn2 * d1 + C2v;                                        \
        f32x2 F3  = sq + C1v;                                                \
        f32x2 d2  = k49 * ws - sq;                                           \
        f32x2 F4  = covn1 * d2 + C2v;                                        \
        f32x2 den = F3 * F4;                                                 \
        f32x2 num = F1 * F2;                                                 \
        f32x2 rv  = {__builtin_amdgcn_rcpf(den.x),                           \
                     __builtin_amdgcn_rcpf(den.y)};                          \
        acc2 += num * rv * vmv;                                              \
    }

    // running row pointers (strength-reduced addresses)
    const float* pxi = px + (size_t)(oy0 + 6) * Wc;
    const float* pyi = py + (size_t)(oy0 + 6) * Wc;
    const float* pxo = px + (size_t)oy0 * Wc;
    const float* pyo = py + (size_t)oy0 * Wc;

    #pragma unroll 4
    for (int tt = 0; tt < nvalid; ++tt) {
        f32x4 xi = *(const f32x4*)pxi; pxi += Wc;
        f32x4 yi = *(const f32x4*)pyi; pyi += Wc;
        VADD(xi, yi)
        float Wx0, Wx1, Wx2, Wx3;  H7(Vx,  Wx0, Wx1, Wx2, Wx3)
        float Wy0, Wy1, Wy2, Wy3;  H7(Vy,  Wy0, Wy1, Wy2, Wy3)
        float Wp0, Wp1, Wp2, Wp3;  H7(Vxy, Wp0, Wp1, Wp2, Wp3)
        float Ws0, Ws1, Ws2, Ws3;  H7(Vss, Ws0, Ws1, Ws2, Ws3)
        f32x2 wx01 = {Wx0, Wx1}, wx23 = {Wx2, Wx3};
        f32x2 wy01 = {Wy0, Wy1}, wy23 = {Wy2, Wy3};
        f32x2 wp01 = {Wp0, Wp1}, wp23 = {Wp2, Wp3};
        f32x2 ws01 = {Ws0, Ws1}, ws23 = {Ws2, Ws3};
        SSIM2(wx01, wy01, wp01, ws01, vm01)
        SSIM2(wx23, wy23, wp23, ws23, vm23)
        f32x4 xo = *(const f32x4*)pxo; pxo += Wc;
        f32x4 yo = *(const f32x4*)pyo; pyo += Wc;
        VSUB(xo, yo)
    }

    #undef SSIM2
    #undef H7
    #undef VADD
    #undef VSUB

    float acc = acc2.x + acc2.y;
    // deterministic wave reduce + cross-wave LDS fold (one partial per block)
    #pragma unroll
    for (int off = 1; off < 64; off <<= 1)
        acc += __shfl_xor(acc, off, 64);
    __shared__ float sacc[4];
    if (lane == 0) sacc[wid] = acc;
    __syncthreads();
    if (threadIdx.x == 0)
        part[lin] = (sacc[0] + sacc[1]) + (sacc[2] + sacc[3]);
}

// ---------------- Kernel 3: final deterministic f64 reduction ---------------
__global__ __launch_bounds__(1024) void final_reduce_kernel(
    const float* __restrict__ part, float* __restrict__ out)
{
    __shared__ double sd[1024];
    double s = 0.0;
    for (int i = threadIdx.x; i < NPART; i += 1024)
        s += (double)part[i];
    sd[threadIdx.x] = s;
    __syncthreads();
    for (int off = 512; off > 0; off >>= 1) {
        if (threadIdx.x < off) sd[threadIdx.x] += sd[threadIdx.x + off];
        __syncthreads();
    }
    if (threadIdx.x == 0)
        out[0] = (float)(sd[0] / ((double)BATCH * OH * OW));
}

extern "C" void kernel_launch(void* const* d_in, const int* in_sizes, int n_in,
                              void* d_out, int out_size, void* d_ws, size_t ws_size,
                              hipStream_t stream) {
    const float* X = (const float*)d_in[0];
    const float* Y = (const float*)d_in[1];
    float* out = (float*)d_out;
    float* ws  = (float*)d_ws;

    float* mmpart = ws;                   // 2 * BATCH * CHUNKS = 4096 floats
    float* part   = ws + 4096;            // NPART = 1536 floats

    mm_part_kernel<<<BATCH * CHUNKS, 256, 0, stream>>>(X, Y, mmpart);
    ssim_stream_kernel<<<NBLK, 64 * WPB, 0, stream>>>(X, Y, mmpart, part);
    final_reduce_kernel<<<1, 1024, 0, stream>>>(part, out);
}